// Round 2
// baseline (278.985 us; speedup 1.0000x reference)
//
#include <hip/hip_runtime.h>

// B-spline basis, DF=16, DEGREE=3, fixed knots:
// KNOTS = [0,0,0] ++ linspace(0, 1+1e-7, 14) ++ [1,1,1]   (20 knots)
// Output shape (32, 131072, 16) float32.
// Memory-bound: 268 MB out + 17 MB in => ~45 us floor at 6.4 TB/s.
//
// R1: per-thread row stores -> 64 partial sector writes/instr -> ~3 TB/s.
// R2: quad-shuffle transpose -> 256B-strided wave footprint. Worst round.
// R3: LDS transpose + output-linear drain (1KB contiguous per wave-instr,
//     fillBuffer pattern) -> WIN.
// R4: nontemporal loads/stores.
// R5: dense Cox-de Boor triangle (~420 VALU/elem) -> local-support de Boor
//     (4 nonzero bases, ~80 VALU/elem, rcpf). Total delta: -0.2us = noise.
//     CONCLUSION: compute is NOT the limiter. Residual ~100us over the
//     ~167us harness fill = ~2.9 TB/s effective, vs fill's 6.4 TB/s.
// R6 (this round): memory-path restructure.
//     (a) Drop nontemporal stores -- fillBuffer (the 6.4 TB/s reference on
//         this chip) uses plain streaming stores; 268MB >> 32MB L2 streams
//         to HBM at full rate regardless; nt was the one untested deviation.
//     (b) 4 chunks per wave: wave count 65536 -> 16384. All 4 input loads
//         issued up-front (independent, latency-overlapped), then
//         4x {compute -> LDS transpose -> 4x contiguous 1KB plain stores}.
//         Amortizes kernarg/setup/load-latency 4x. LDS stays 20KB/block
//         (8 blocks/CU). Same-wave DS ops to aliasing addresses are
//         in-order -> no barrier needed across chunk iterations.

typedef float vfloat4 __attribute__((ext_vector_type(4)));

// Row stride 5 vfloat4 (4 data + 1 pad) = 20 floats: lane l's row starts at
// bank (20*l)%32, uniform spread over banks in both LDS phases. 64 rows x
// 80B = 5 KB/wave, 20 KB/block -> 8 blocks/CU (full occupancy).
#define ROW_STRIDE 5
#define CHUNKS 4

__global__ __launch_bounds__(256) void bspline_basis_kernel(
    const float* __restrict__ ts, float* __restrict__ out, int n)
{
    // Interior knots are uniform with spacing STEP; the triple knots at the
    // ends are reproduced by clamping the linear formula.
    constexpr float STEP     = (float)((1.0 + 1e-07) / 13.0);
    constexpr float INV_STEP = (float)(13.0 / (1.0 + 1e-07));

    __shared__ vfloat4 lds[4][64 * ROW_STRIDE];

    const int tid  = threadIdx.x;
    const int wave = tid >> 6;
    const int lane = tid & 63;

    // Each wave owns CHUNKS consecutive 64-element chunks (256 elements,
    // 16 KB of output).
    const size_t wave_e0 =
        ((size_t)blockIdx.x * 4 + (size_t)wave) * (64 * CHUNKS);

    // ---- Up-front input: 4 independent coalesced 256B wave-loads ----
    float tin[CHUNKS];
#pragma unroll
    for (int j = 0; j < CHUNKS; ++j) {
        size_t e = wave_e0 + (size_t)(j * 64 + lane);
        if (e >= (size_t)n) e = (size_t)n - 1;
        tin[j] = ts[e];
    }

    const size_t limit4 = (size_t)n * 4;
    vfloat4* const obase = reinterpret_cast<vfloat4*>(out);

#pragma unroll
    for (int j = 0; j < CHUNKS; ++j) {
        float t = tin[j];

        // ---- local-support de Boor: 4 nonzero bases at interval d ----
        // t in [knot[d+3], knot[d+4]), d in [0,12]. Boundary
        // misclassification (~1 ulp) covered by C2 continuity (~1e-6 err).
        int d = (int)(t * INV_STEP);
        d = d < 0 ? 0 : (d > 12 ? 12 : d);
        float df = (float)d;

        // knot[d+3+o] = clamp(STEP*(d+o), 0, 1).
        float km2 = fmaxf(STEP * (df - 2.0f), 0.0f);
        float km1 = fmaxf(STEP * (df - 1.0f), 0.0f);
        float k0  = STEP * df;
        float kp1 = STEP * (df + 1.0f);
        float kp2 = fminf(STEP * (df + 2.0f), 1.0f);
        float kp3 = fminf(STEP * (df + 3.0f), 1.0f);

        float l1 = t - k0, l2 = t - km1, l3 = t - km2;
        float r1 = kp1 - t, r2 = kp2 - t, r3 = kp3 - t;

        float N0, N1, N2, N3;
        {   // p = 1
            float t0 = __builtin_amdgcn_rcpf(r1 + l1);
            N0 = r1 * t0;
            N1 = l1 * t0;
        }
        {   // p = 2
            float t0 = N0 * __builtin_amdgcn_rcpf(r1 + l2);
            N0 = r1 * t0;
            float sv = l2 * t0;
            float t1 = N1 * __builtin_amdgcn_rcpf(r2 + l1);
            N1 = sv + r2 * t1;
            N2 = l1 * t1;
        }
        {   // p = 3
            float t0 = N0 * __builtin_amdgcn_rcpf(r1 + l3);
            N0 = r1 * t0;
            float sv = l3 * t0;
            float t1 = N1 * __builtin_amdgcn_rcpf(r2 + l2);
            N1 = sv + r2 * t1;
            sv = l2 * t1;
            float t2 = N2 * __builtin_amdgcn_rcpf(r3 + l1);
            N2 = sv + r3 * t2;
            N3 = l1 * t2;
        }

        // Row = 12 zeros + N0..N3 at positions d..d+3 (d+3 <= 15).
        vfloat4* rowv = &lds[wave][lane * ROW_STRIDE];
        rowv[0] = (vfloat4){0.0f, 0.0f, 0.0f, 0.0f};
        rowv[1] = (vfloat4){0.0f, 0.0f, 0.0f, 0.0f};
        rowv[2] = (vfloat4){0.0f, 0.0f, 0.0f, 0.0f};
        rowv[3] = (vfloat4){0.0f, 0.0f, 0.0f, 0.0f};
        float* rowf = reinterpret_cast<float*>(rowv);
        rowf[d]     = N0;
        rowf[d + 1] = N1;
        rowf[d + 2] = N2;
        rowf[d + 3] = N3;

        // ---- Drain chunk j in output-linear order: 4x contiguous 1KB
        // wave spans, plain streaming stores (fillBuffer pattern). Same-wave
        // ds_write->ds_read dependency ordered by lgkmcnt; chunk j+1's
        // ds_writes can't pass chunk j's ds_reads (same addresses, per-wave
        // in-order LDS).
        const size_t cbase4 = (wave_e0 + (size_t)(j * 64)) * 4;
        vfloat4* o = obase + cbase4;
#pragma unroll
        for (int m = 0; m < 4; ++m) {
            int idx = lane + 64 * m;          // chunk-local vfloat4 index
            int e = idx >> 2;                 // source row in this wave's LDS
            int l = idx & 3;                  // quarter of the row
            vfloat4 v = lds[wave][e * ROW_STRIDE + l];
            if (cbase4 + (size_t)idx < limit4) {
                o[idx] = v;
            }
        }
    }
}

extern "C" void kernel_launch(void* const* d_in, const int* in_sizes, int n_in,
                              void* d_out, int out_size, void* d_ws, size_t ws_size,
                              hipStream_t stream) {
    const float* ts = (const float*)d_in[0];
    float* out = (float*)d_out;
    int n = in_sizes[0];  // 32 * 131072 = 4194304

    const int block = 256;
    const int elems_per_block = block * CHUNKS;   // 1024
    const int grid = (n + elems_per_block - 1) / elems_per_block;
    bspline_basis_kernel<<<grid, block, 0, stream>>>(ts, out, n);
}